// Round 21
// baseline (341.731 us; speedup 1.0000x reference)
//
#include <hip/hip_runtime.h>
#include <stdint.h>

#define N_TOK 8192
#define HDIM  1024
#define NEXP  8
#define CAP   16384   // per-expert rowid list capacity
#define S0    96      // per-role descriptor stride, gemm0 (>= sum_e ceil(nt_e/2)*2, nt in 256-row units)
#define S1    64      // per-role descriptor stride, gemm1 (>= sum_e ceil(nt_e/4)*2)

typedef __bf16 bf16x8 __attribute__((ext_vector_type(8)));
typedef float  f32x4  __attribute__((ext_vector_type(4)));

__device__ inline unsigned short f2bf(float f) {
  union { float f; unsigned u; } v; v.f = f;
  return (unsigned short)((v.u + 0x7fffu + ((v.u >> 16) & 1u)) >> 16);  // RNE
}

__device__ inline float bf2f(unsigned short b) {
  union { unsigned u; float f; } v; v.u = (unsigned)b << 16; return v.f;
}

// tanh-form gelu (max |err| vs exact erf-gelu ~1e-3, far under 2.7e-2 threshold)
__device__ inline float gelu_f(float x) {
  float y = 0.7978845608028654f * (x + 0.044715f * x * x * x);
  y = fminf(fmaxf(y, -15.f), 15.f);
  float t = __expf(2.f * y);
  return 0.5f * x * (1.f + (t - 1.f) / (t + 1.f));
}

__device__ inline void gld_lds16(const void* gptr, void* lptr) {
  __builtin_amdgcn_global_load_lds(
      (const __attribute__((address_space(1))) void*)(uintptr_t)gptr,
      (__attribute__((address_space(3))) void*)(uintptr_t)lptr,
      16, 0, 0);
}

// -------- f32 -> bf16 conversion, both weight tensors in ONE dispatch -------
__global__ __launch_bounds__(256) void cvt2_kernel(
    const float* __restrict__ s1, unsigned short* __restrict__ d1, int n1,
    const float* __restrict__ s2, unsigned short* __restrict__ d2, int n2) {
  int i = blockIdx.x * 256 + threadIdx.x;
  int stride = gridDim.x * 256;
  for (; i < n1 + n2; i += stride) {
    const float4* sp; ushort4* dp; int k;
    if (i < n1) { sp = (const float4*)s1; dp = (ushort4*)d1; k = i; }
    else        { sp = (const float4*)s2; dp = (ushort4*)d2; k = i - n1; }
    float4 v = sp[k];
    ushort4 o;
    o.x = f2bf(v.x); o.y = f2bf(v.y); o.z = f2bf(v.z); o.w = f2bf(v.w);
    dp[k] = o;
  }
}

// ---------------- router: logits, top-2, softmax -> pair/probs (NO atomics) ----------------
__global__ __launch_bounds__(256) void router_kernel(
    const float* __restrict__ tokens, const float* __restrict__ rw,
    unsigned short* __restrict__ tokb, int* __restrict__ pair,
    float* __restrict__ probs) {
  int wid = threadIdx.x >> 6, lane = threadIdx.x & 63;
  int n = blockIdx.x * 4 + wid;
  const float4* trow = (const float4*)(tokens + (size_t)n * HDIM);
  ushort4* tdst = (ushort4*)(tokb + (size_t)n * HDIM);
  float acc[NEXP];
#pragma unroll
  for (int e = 0; e < NEXP; e++) acc[e] = 0.f;
#pragma unroll
  for (int it = 0; it < 4; it++) {
    int c4 = it * 64 + lane;
    float4 tv = trow[c4];
    ushort4 o;
    o.x = f2bf(tv.x); o.y = f2bf(tv.y); o.z = f2bf(tv.z); o.w = f2bf(tv.w);
    tdst[c4] = o;
#pragma unroll
    for (int e = 0; e < NEXP; e++) {
      float4 w = ((const float4*)(rw + e * HDIM))[c4];
      acc[e] += tv.x * w.x + tv.y * w.y + tv.z * w.z + tv.w * w.w;
    }
  }
#pragma unroll
  for (int e = 0; e < NEXP; e++) {
#pragma unroll
    for (int off = 32; off > 0; off >>= 1) acc[e] += __shfl_xor(acc[e], off, 64);
  }
  if (lane == 0) {
    int e0 = 0; float s0 = acc[0];
#pragma unroll
    for (int e = 1; e < NEXP; e++) if (acc[e] > s0) { s0 = acc[e]; e0 = e; }
    int e1 = -1; float s1 = -3.4e38f;
#pragma unroll
    for (int e = 0; e < NEXP; e++) if (e != e0 && acc[e] > s1) { s1 = acc[e]; e1 = e; }
    float z  = expf(s1 - s0);
    float p0 = 1.f / (1.f + z);
    pair[n] = e0 | (e1 << 8);
    probs[2 * n]     = p0;
    probs[2 * n + 1] = z * p0;
  }
}

// ---------------- dispatch: deterministic per-expert compaction via LDS scan ----------------
__global__ __launch_bounds__(1024) void dispatch_kernel(
    const int* __restrict__ pair, int* __restrict__ counts,
    int* __restrict__ rowids) {
  int e = blockIdx.x;
  int t = threadIdx.x;
  __shared__ int sc[1024];
  int p8[8];
  int c = 0;
#pragma unroll
  for (int i = 0; i < 8; i++) {
    p8[i] = pair[t * 8 + i];
    c += ((p8[i] & 255) == e) + (((p8[i] >> 8) & 255) == e);
  }
  sc[t] = c;
  __syncthreads();
  for (int off = 1; off < 1024; off <<= 1) {
    int v = (t >= off) ? sc[t - off] : 0;
    __syncthreads();
    sc[t] += v;
    __syncthreads();
  }
  if (t == 1023) counts[e] = sc[1023];
  int* dst = rowids + e * CAP + (sc[t] - c);
#pragma unroll
  for (int i = 0; i < 8; i++) {
    int n = t * 8 + i;
    if ((p8[i] & 255) == e)        *dst++ = 2 * n;
    if (((p8[i] >> 8) & 255) == e) *dst++ = 2 * n + 1;
  }
}

// ---- worklist: per-XCD-role descriptor lists, 256-row tiles, 2-D operand partition ----
// gemm0 (CB=8 slices of 256 cols): role r = (h<<2)|q: tile-half h, cb-pair q ({2q,2q+1}).
// gemm1 (CB=4): role r = (tq<<1)|cp: tile-quarter tq, cb-pair cp ({2cp,2cp+1}).
// Order within role: expert-major, tile, the role's 2 cbs back-to-back (A-panel L2-hot).
// desc = (e<<24) | (tile<<8) | cb
__global__ void worklist_kernel(const int* __restrict__ counts,
                                int* __restrict__ wlb0, int* __restrict__ cnt0,
                                int* __restrict__ wlb1, int* __restrict__ cnt1) {
  int r = threadIdx.x;
  if (r < 8) {
    int h = r >> 2, q = r & 3;
    int p = 0;
    for (int e = 0; e < NEXP; e++) {
      int nt = (counts[e] + 255) >> 8;
      int h0 = (nt + 1) >> 1;
      int t0 = h ? h0 : 0, t1 = h ? nt : h0;
      for (int ti = t0; ti < t1; ti++)
        for (int c = 0; c < 2; c++)
          wlb0[r * S0 + p++] = (e << 24) | (ti << 8) | (q * 2 + c);
    }
    cnt0[r] = p;

    int tq = r >> 1, cp = r & 1;
    p = 0;
    for (int e = 0; e < NEXP; e++) {
      int nt = (counts[e] + 255) >> 8;
      int b0 = (nt * tq) >> 2, b1 = (nt * (tq + 1)) >> 2;
      for (int ti = b0; ti < b1; ti++)
        for (int c = 0; c < 2; c++)
          wlb1[r * S1 + p++] = (e << 24) | (ti << 8) | (cp * 2 + c);
    }
    cnt1[r] = p;
  }
}

// --- gathered NT bf16 GEMM: 256x256 tile, BK=64 dbuf counted-vmcnt, 1024 thr, 16x(64x64) ---
// LDS-read traffic per FLOP halved vs 32x32 waves: per ks, af[4]+bfv[4] (8 reads) feed 16
// MFMAs. 2x64KB dbuf = 128 KB -> 1 block/CU x 16 waves (4/SIMD). Counted vmcnt keeps 4
// loads/thread in flight across barriers (R17-proven schedule; no vmcnt(0) in loop).
template <int MODE>
__global__ __launch_bounds__(1024) void moe_gemm(
    const unsigned short* __restrict__ Abase,
    const unsigned short* __restrict__ Wb,
    const float* __restrict__ bias,
    const int* __restrict__ counts, const int* __restrict__ rowids,
    const int* __restrict__ wlb, const int* __restrict__ cnt,
    const float* __restrict__ probs,
    unsigned short* __restrict__ dstbuf) {
  constexpr int KT     = MODE ? 32 : 16;   // K / 64
  constexpr int NCOL   = MODE ? 1024 : 2048;
  constexpr int KDIM   = MODE ? 2048 : 1024;
  constexpr int STRIDE = MODE ? S1 : S0;

  int role = blockIdx.x & 7;               // XCD pin
  int j    = blockIdx.x >> 3;
  if (j >= cnt[role]) return;
  int desc = wlb[role * STRIDE + j];
  int e  = desc >> 24;
  int rb = (desc >> 8) & 0xffff;           // 256-row units
  int cb = desc & 255;                     // 256-col slice
  int ce = counts[e];
  const int* rl = rowids + e * CAP + rb * 256;

  int t = threadIdx.x;
  // double buffer: per buf A[256][64]bf16 (32 KB) @0, B[256][64] @32768 -> 64 KB/buf
  __shared__ __align__(16) char smem[131072];

  // staging: 4 chunks/thread (2 A + 2 B). chunk c -> byte c*16; row=c>>3, phys col=c&7;
  // source logical chunk jsrc = (c&7)^((c>>3)&7) = (t&7)^((t>>3)&7) (rows t>>3, 128+(t>>3))
  int jsrc = (t & 7) ^ ((t >> 3) & 7);
  const char* asrc[2];
  const char* bsrc[2];
#pragma unroll
  for (int i = 0; i < 2; i++) {
    int rr = i * 128 + (t >> 3);
    int rid = (rb * 256 + rr < ce) ? rl[rr] : rl[0];   // clamp tail to a valid row
    long arow = MODE ? (long)rid : (long)(rid >> 1);
    asrc[i] = (const char*)(Abase + arow * KDIM) + jsrc * 16;
    bsrc[i] = (const char*)(Wb + ((long)e * NCOL + cb * 256 + rr) * KDIM) + jsrc * 16;
  }

  auto stage = [&](int kt, char* buf) {
#pragma unroll
    for (int i = 0; i < 2; i++)
      gld_lds16(asrc[i] + kt * 128, buf + i * 16384 + t * 16);
#pragma unroll
    for (int i = 0; i < 2; i++)
      gld_lds16(bsrc[i] + kt * 128, buf + 32768 + i * 16384 + t * 16);
  };

  f32x4 acc[4][4];
#pragma unroll
  for (int mi = 0; mi < 4; mi++)
#pragma unroll
    for (int ni = 0; ni < 4; ni++) {
      f32x4 z = {0.f, 0.f, 0.f, 0.f};
      acc[mi][ni] = z;
    }

  int lane = t & 63, wid = t >> 6;
  int wr = wid >> 2, wc = wid & 3;        // 4x4 wave grid; per-wave 64 rows x 64 cols
  int lr = lane >> 4, lc = lane & 15;

  // prologue: tiles 0,1 in flight (8 loads/thread)
  stage(0, smem);
  stage(1, smem + 65536);

  for (int kt = 0; kt < KT; kt++) {
    if (kt + 1 < KT) {
      asm volatile("s_waitcnt vmcnt(4)" ::: "memory");   // tile kt landed; kt+1 in flight
    } else {
      asm volatile("s_waitcnt vmcnt(0)" ::: "memory");   // last tile
    }
    __builtin_amdgcn_s_barrier();
    __builtin_amdgcn_sched_barrier(0);
    char* cbuf = smem + ((kt & 1) << 16);
#pragma unroll
    for (int ks = 0; ks < 2; ks++) {
      bf16x8 af[4], bfv[4];
      int jj = ks * 4 + lr;
#pragma unroll
      for (int mi = 0; mi < 4; mi++) {
        int rr = wr * 64 + mi * 16 + lc;
        af[mi] = *(const bf16x8*)(cbuf + rr * 128 + ((jj ^ (rr & 7)) << 4));
      }
#pragma unroll
      for (int ni = 0; ni < 4; ni++) {
        int rr = wc * 64 + ni * 16 + lc;
        bfv[ni] = *(const bf16x8*)(cbuf + 32768 + rr * 128 + ((jj ^ (rr & 7)) << 4));
      }
      __builtin_amdgcn_s_setprio(1);
#pragma unroll
      for (int mi = 0; mi < 4; mi++)
#pragma unroll
        for (int ni = 0; ni < 4; ni++)
          acc[mi][ni] = __builtin_amdgcn_mfma_f32_16x16x32_bf16(af[mi], bfv[ni], acc[mi][ni], 0, 0, 0);
      __builtin_amdgcn_s_setprio(0);
    }
    __builtin_amdgcn_s_barrier();          // all waves done reading buf[kt&1]
    __builtin_amdgcn_sched_barrier(0);
    if (kt + 2 < KT) stage(kt + 2, cbuf);  // overwrite consumed buffer; 4 new loads
  }

  // ---- epilogue: stage C (256x256 bf16 = 128 KB = full smem), chunk-swizzled ----
  float bcol[4];
#pragma unroll
  for (int ni = 0; ni < 4; ni++)
    bcol[ni] = bias[e * NCOL + cb * 256 + wc * 64 + ni * 16 + lc];

#pragma unroll
  for (int mi = 0; mi < 4; mi++) {
#pragma unroll
    for (int r4 = 0; r4 < 4; r4++) {
      int lrow = wr * 64 + mi * 16 + lr * 4 + r4;      // 0..255
      float p = 1.f;
      if constexpr (MODE == 1)
        p = (rb * 256 + lrow < ce) ? probs[rl[lrow]] : 0.f;
#pragma unroll
      for (int ni = 0; ni < 4; ni++) {
        int col = wc * 64 + ni * 16 + lc;              // 0..255
        float x = acc[mi][ni][r4] + bcol[ni];
        if constexpr (MODE == 0)
          x = gelu_f(x);
        else
          x *= p;
        int jc = col >> 3;   // 16B chunk within 512B row; swizzle vs row
        *(unsigned short*)(smem + lrow * 512 + ((jc ^ (lrow & 31)) << 4) + (col & 7) * 2) = f2bf(x);
      }
    }
  }
  __syncthreads();

  int row = t >> 2, q = t & 3;   // 4 threads/row, 128B each
  if (rb * 256 + row < ce) {
    int rid = rl[row];
    char* dst = (char*)(dstbuf + (long)rid * NCOL + cb * 256) + q * 128;
#pragma unroll
    for (int i = 0; i < 8; i++) {
      int jc = q * 8 + i;
      *(int4*)(dst + i * 16) = *(const int4*)(smem + row * 512 + ((jc ^ (row & 31)) << 4));
    }
  }
}

// ---------------- merge: out[n] = Y[2n] + Y[2n+1]  (bf16 -> f32) ----------------
typedef short short8v __attribute__((ext_vector_type(8)));
__global__ __launch_bounds__(256) void merge_kernel(const unsigned short* __restrict__ Y,
                                                    float* __restrict__ out) {
  int i = blockIdx.x * 256 + threadIdx.x;   // 1M chunks of 8 elems
  int n = i >> 7, c = (i & 127) * 8;
  const short8v a = *(const short8v*)(Y + (long)(2 * n) * HDIM + c);
  const short8v b = *(const short8v*)(Y + (long)(2 * n + 1) * HDIM + c);
  float4 o0, o1;
#pragma unroll
  for (int k = 0; k < 8; k++) {
    float v = bf2f((unsigned short)a[k]) + bf2f((unsigned short)b[k]);
    if (k < 4) (&o0.x)[k] = v; else (&o1.x)[k - 4] = v;
  }
  float4* dst = (float4*)(out + (long)n * HDIM + c);
  dst[0] = o0; dst[1] = o1;
}

extern "C" void kernel_launch(void* const* d_in, const int* in_sizes, int n_in,
                              void* d_out, int out_size, void* d_ws, size_t ws_size,
                              hipStream_t stream) {
  const float* tokens   = (const float*)d_in[0];
  const float* router_w = (const float*)d_in[1];
  const float* w1       = (const float*)d_in[2];
  const float* b1       = (const float*)d_in[3];
  const float* w2       = (const float*)d_in[4];
  const float* b2       = (const float*)d_in[5];
  float* out = (float*)d_out;

  // ws layout (bytes):
  //   0        counts[8]
  //   64       rowids[8][16384] int          (512 KiB)
  //   +512K    probs[16384] f32              (64 KiB)
  //   +64K     pair[8192] int                (32 KiB)
  //   then     cnt0[8], cnt1[8], wlb0[8*S0], wlb1[8*S1]  (~5 KiB)
  //   1 MiB    tokens_bf16 [8192][1024]      (16 MiB)
  //   +16M     w1b [8][2048][1024] bf16      (32 MiB)  <- becomes Ybuf after gemm0
  //   +48M     w2b [8][1024][2048] bf16      (32 MiB)
  //   +80M     Hbuf [16384][2048] bf16       (64 MiB)   total ~145 MiB
  char* ws = (char*)d_ws;
  int*            counts = (int*)ws;
  int*            rowids = (int*)(ws + 64);
  float*          probs  = (float*)(ws + 64 + NEXP * CAP * 4);
  int*            pair   = (int*)(ws + 64 + NEXP * CAP * 4 + N_TOK * 2 * 4);
  char*           wlbase = ws + 64 + NEXP * CAP * 4 + N_TOK * 2 * 4 + N_TOK * 4;
  int*            cnt0   = (int*)wlbase;
  int*            cnt1   = (int*)(wlbase + 64);
  int*            wlb0   = (int*)(wlbase + 128);
  int*            wlb1   = (int*)(wlbase + 128 + 8 * S0 * 4);
  unsigned short* tokb   = (unsigned short*)(ws + (1u << 20));
  unsigned short* w1b    = (unsigned short*)(ws + (1u << 20) + 16777216u);
  unsigned short* w2b    = (unsigned short*)(ws + (1u << 20) + 16777216u + 33554432u);
  unsigned short* Hbuf   = (unsigned short*)(ws + (1u << 20) + 16777216u + 67108864u);
  unsigned short* Ybuf   = w1b;  // w1 weights dead after gemm0; 32 MiB = 16384x1024 bf16

  cvt2_kernel<<<4096, 256, 0, stream>>>(w1, w1b, NEXP * 2048 * 1024 / 4,
                                        w2, w2b, NEXP * 1024 * 2048 / 4);
  router_kernel<<<N_TOK / 4, 256, 0, stream>>>(tokens, router_w, tokb, pair, probs);
  dispatch_kernel<<<NEXP, 1024, 0, stream>>>(pair, counts, rowids);
  worklist_kernel<<<1, 64, 0, stream>>>(counts, wlb0, cnt0, wlb1, cnt1);
  moe_gemm<0><<<8 * S0, 1024, 0, stream>>>(tokb, w1b, b1, counts, rowids, wlb0, cnt0, probs, Hbuf);
  moe_gemm<1><<<8 * S1, 1024, 0, stream>>>(Hbuf, w2b, b2, counts, rowids, wlb1, cnt1, probs, Ybuf);
  merge_kernel<<<N_TOK * HDIM / 8 / 256, 256, 0, stream>>>(Ybuf, out);
}

// Round 22
// 272.973 us; speedup vs baseline: 1.2519x; 1.2519x over previous
//
#include <hip/hip_runtime.h>
#include <stdint.h>

#define N_TOK 8192
#define HDIM  1024
#define NEXP  8
#define CAP   16384   // per-expert rowid list capacity
#define S0    320     // per-role descriptor stride, gemm0 (>= sum_e ceil(nt_e/2)*4 = 288)
#define S1    192     // per-role descriptor stride, gemm1 (>= sum_e ceil(nt_e/4)*4 = 160)

typedef __bf16 bf16x8 __attribute__((ext_vector_type(8)));
typedef float  f32x4  __attribute__((ext_vector_type(4)));

__device__ inline unsigned short f2bf(float f) {
  union { float f; unsigned u; } v; v.f = f;
  return (unsigned short)((v.u + 0x7fffu + ((v.u >> 16) & 1u)) >> 16);  // RNE
}

__device__ inline float bf2f(unsigned short b) {
  union { unsigned u; float f; } v; v.u = (unsigned)b << 16; return v.f;
}

// tanh-form gelu (max |err| vs exact erf-gelu ~1e-3, far under 2.7e-2 threshold)
__device__ inline float gelu_f(float x) {
  float y = 0.7978845608028654f * (x + 0.044715f * x * x * x);
  y = fminf(fmaxf(y, -15.f), 15.f);
  float t = __expf(2.f * y);
  return 0.5f * x * (1.f + (t - 1.f) / (t + 1.f));
}

__device__ inline void gld_lds16(const void* gptr, void* lptr) {
  __builtin_amdgcn_global_load_lds(
      (const __attribute__((address_space(1))) void*)(uintptr_t)gptr,
      (__attribute__((address_space(3))) void*)(uintptr_t)lptr,
      16, 0, 0);
}

// -------- f32 -> bf16 conversion, both weight tensors in ONE dispatch -------
__global__ __launch_bounds__(256) void cvt2_kernel(
    const float* __restrict__ s1, unsigned short* __restrict__ d1, int n1,
    const float* __restrict__ s2, unsigned short* __restrict__ d2, int n2) {
  int i = blockIdx.x * 256 + threadIdx.x;
  int stride = gridDim.x * 256;
  for (; i < n1 + n2; i += stride) {
    const float4* sp; ushort4* dp; int k;
    if (i < n1) { sp = (const float4*)s1; dp = (ushort4*)d1; k = i; }
    else        { sp = (const float4*)s2; dp = (ushort4*)d2; k = i - n1; }
    float4 v = sp[k];
    ushort4 o;
    o.x = f2bf(v.x); o.y = f2bf(v.y); o.z = f2bf(v.z); o.w = f2bf(v.w);
    dp[k] = o;
  }
}

// ---------------- router: logits, top-2, softmax -> pair/probs (NO atomics) ----------------
__global__ __launch_bounds__(256) void router_kernel(
    const float* __restrict__ tokens, const float* __restrict__ rw,
    unsigned short* __restrict__ tokb, int* __restrict__ pair,
    float* __restrict__ probs) {
  int wid = threadIdx.x >> 6, lane = threadIdx.x & 63;
  int n = blockIdx.x * 4 + wid;
  const float4* trow = (const float4*)(tokens + (size_t)n * HDIM);
  ushort4* tdst = (ushort4*)(tokb + (size_t)n * HDIM);
  float acc[NEXP];
#pragma unroll
  for (int e = 0; e < NEXP; e++) acc[e] = 0.f;
#pragma unroll
  for (int it = 0; it < 4; it++) {
    int c4 = it * 64 + lane;
    float4 tv = trow[c4];
    ushort4 o;
    o.x = f2bf(tv.x); o.y = f2bf(tv.y); o.z = f2bf(tv.z); o.w = f2bf(tv.w);
    tdst[c4] = o;
#pragma unroll
    for (int e = 0; e < NEXP; e++) {
      float4 w = ((const float4*)(rw + e * HDIM))[c4];
      acc[e] += tv.x * w.x + tv.y * w.y + tv.z * w.z + tv.w * w.w;
    }
  }
#pragma unroll
  for (int e = 0; e < NEXP; e++) {
#pragma unroll
    for (int off = 32; off > 0; off >>= 1) acc[e] += __shfl_xor(acc[e], off, 64);
  }
  if (lane == 0) {
    int e0 = 0; float s0 = acc[0];
#pragma unroll
    for (int e = 1; e < NEXP; e++) if (acc[e] > s0) { s0 = acc[e]; e0 = e; }
    int e1 = -1; float s1 = -3.4e38f;
#pragma unroll
    for (int e = 0; e < NEXP; e++) if (e != e0 && acc[e] > s1) { s1 = acc[e]; e1 = e; }
    float z  = expf(s1 - s0);
    float p0 = 1.f / (1.f + z);
    pair[n] = e0 | (e1 << 8);
    probs[2 * n]     = p0;
    probs[2 * n + 1] = z * p0;
  }
}

// ---------------- dispatch: deterministic per-expert compaction via LDS scan ----------------
__global__ __launch_bounds__(1024) void dispatch_kernel(
    const int* __restrict__ pair, int* __restrict__ counts,
    int* __restrict__ rowids) {
  int e = blockIdx.x;
  int t = threadIdx.x;
  __shared__ int sc[1024];
  int p8[8];
  int c = 0;
#pragma unroll
  for (int i = 0; i < 8; i++) {
    p8[i] = pair[t * 8 + i];
    c += ((p8[i] & 255) == e) + (((p8[i] >> 8) & 255) == e);
  }
  sc[t] = c;
  __syncthreads();
  for (int off = 1; off < 1024; off <<= 1) {
    int v = (t >= off) ? sc[t - off] : 0;
    __syncthreads();
    sc[t] += v;
    __syncthreads();
  }
  if (t == 1023) counts[e] = sc[1023];
  int* dst = rowids + e * CAP + (sc[t] - c);
#pragma unroll
  for (int i = 0; i < 8; i++) {
    int n = t * 8 + i;
    if ((p8[i] & 255) == e)        *dst++ = 2 * n;
    if (((p8[i] >> 8) & 255) == e) *dst++ = 2 * n + 1;
  }
}

// ---- worklist: per-XCD-role block descriptor lists (2-D operand partition) ----
// gemm0 role r: tile-half h=r>>2, cb-quad q=r&3 (cb in {4q..4q+3}, CB=16).
// gemm1 role r: tile-quarter tq=r>>1, cb-pair cp=r&1 (cb in {4cp..4cp+3}, CB=8).
// Order within role: expert-major, tile, then the role's 4 cb back-to-back (A-panel L2-hot).
// desc = (e<<24) | (tile<<8) | cb
__global__ void worklist_kernel(const int* __restrict__ counts,
                                int* __restrict__ wlb0, int* __restrict__ cnt0,
                                int* __restrict__ wlb1, int* __restrict__ cnt1) {
  int r = threadIdx.x;
  if (r < 8) {
    int h = r >> 2, q = r & 3;
    int p = 0;
    for (int e = 0; e < NEXP; e++) {
      int nt = (counts[e] + 127) >> 7;
      int h0 = (nt + 1) >> 1;
      int t0 = h ? h0 : 0, t1 = h ? nt : h0;
      for (int ti = t0; ti < t1; ti++)
        for (int c = 0; c < 4; c++)
          wlb0[r * S0 + p++] = (e << 24) | (ti << 8) | (q * 4 + c);
    }
    cnt0[r] = p;

    int tq = r >> 1, cp = r & 1;
    p = 0;
    for (int e = 0; e < NEXP; e++) {
      int nt = (counts[e] + 127) >> 7;
      int b0 = (nt * tq) >> 2, b1 = (nt * (tq + 1)) >> 2;
      for (int ti = b0; ti < b1; ti++)
        for (int c = 0; c < 4; c++)
          wlb1[r * S1 + p++] = (e << 24) | (ti << 8) | (cp * 4 + c);
    }
    cnt1[r] = p;
  }
}

// ------- gathered NT bf16 GEMM: 128x128 tile, BK=64 dbuf counted-vmcnt, 1024 THREADS -------
// 16 waves (4x4, 32x32 each, acc[2][2]); 2 blocks/CU x 16 waves -> ~22 waves/CU measured.
// Per K-step: vmcnt(2) -> s_barrier -> ds_read + 8 MFMA/wave -> s_barrier -> stage(t+2).
// Block->work mapping descriptor-driven (role = bid&7 -> XCD pin; j = bid>>3).
template <int MODE>
__global__ __launch_bounds__(1024) void moe_gemm(
    const unsigned short* __restrict__ Abase,
    const unsigned short* __restrict__ Wb,
    const float* __restrict__ bias,
    const int* __restrict__ counts, const int* __restrict__ rowids,
    const int* __restrict__ wlb, const int* __restrict__ cnt,
    const float* __restrict__ probs,
    unsigned short* __restrict__ dstbuf) {
  constexpr int KT     = MODE ? 32 : 16;   // K / 64
  constexpr int NCOL   = MODE ? 1024 : 2048;
  constexpr int KDIM   = MODE ? 2048 : 1024;
  constexpr int STRIDE = MODE ? S1 : S0;

  int role = blockIdx.x & 7;               // XCD pin
  int j    = blockIdx.x >> 3;
  if (j >= cnt[role]) return;
  int desc = wlb[role * STRIDE + j];
  int e  = desc >> 24;
  int rb = (desc >> 8) & 0xffff;
  int cb = desc & 255;
  int ce = counts[e];
  const int* rl = rowids + e * CAP + rb * 128;

  int t = threadIdx.x;
  // double buffer: per buf A[128][64]bf16 (16 KB) @0, B[128][64] @16384 -> 32 KB/buf
  __shared__ __align__(16) char smem[65536];

  // staging: 1024 threads, 1 A-chunk + 1 B-chunk each (16 B). chunk c = t -> byte c*16;
  // row = t>>3, phys col-chunk = t&7; source logical chunk jsrc = (t&7)^((t>>3)&7)
  int jsrc = (t & 7) ^ ((t >> 3) & 7);
  int rr0 = t >> 3;                        // 0..127
  int rid0 = (rb * 128 + rr0 < ce) ? rl[rr0] : rl[0];
  long arow = MODE ? (long)rid0 : (long)(rid0 >> 1);
  const char* asrc = (const char*)(Abase + arow * KDIM) + jsrc * 16;
  const char* bsrc = (const char*)(Wb + ((long)e * NCOL + cb * 128 + rr0) * KDIM) + jsrc * 16;

  auto stage = [&](int kt, char* buf) {
    gld_lds16(asrc + kt * 128, buf + t * 16);
    gld_lds16(bsrc + kt * 128, buf + 16384 + t * 16);
  };

  f32x4 acc[2][2];
#pragma unroll
  for (int mi = 0; mi < 2; mi++)
#pragma unroll
    for (int ni = 0; ni < 2; ni++) {
      f32x4 z = {0.f, 0.f, 0.f, 0.f};
      acc[mi][ni] = z;
    }

  int lane = t & 63, wid = t >> 6;
  int wr = wid >> 2, wc = wid & 3;        // 4x4 wave grid; per-wave 32 rows x 32 cols
  int lr = lane >> 4, lc = lane & 15;

  // prologue: tiles 0,1 in flight (4 loads/thread)
  stage(0, smem);
  stage(1, smem + 32768);

  for (int kt = 0; kt < KT; kt++) {
    if (kt + 1 < KT) {
      asm volatile("s_waitcnt vmcnt(2)" ::: "memory");   // tile kt landed; kt+1 in flight
    } else {
      asm volatile("s_waitcnt vmcnt(0)" ::: "memory");   // last tile
    }
    __builtin_amdgcn_s_barrier();
    __builtin_amdgcn_sched_barrier(0);
    char* cbuf = smem + ((kt & 1) << 15);
#pragma unroll
    for (int ks = 0; ks < 2; ks++) {
      bf16x8 af[2], bfv[2];
      int jj = ks * 4 + lr;
#pragma unroll
      for (int mi = 0; mi < 2; mi++) {
        int rr = wr * 32 + mi * 16 + lc;
        af[mi] = *(const bf16x8*)(cbuf + rr * 128 + ((jj ^ (rr & 7)) << 4));
      }
#pragma unroll
      for (int ni = 0; ni < 2; ni++) {
        int rr = wc * 32 + ni * 16 + lc;
        bfv[ni] = *(const bf16x8*)(cbuf + 16384 + rr * 128 + ((jj ^ (rr & 7)) << 4));
      }
      __builtin_amdgcn_s_setprio(1);
#pragma unroll
      for (int mi = 0; mi < 2; mi++)
#pragma unroll
        for (int ni = 0; ni < 2; ni++)
          acc[mi][ni] = __builtin_amdgcn_mfma_f32_16x16x32_bf16(af[mi], bfv[ni], acc[mi][ni], 0, 0, 0);
      __builtin_amdgcn_s_setprio(0);
    }
    __builtin_amdgcn_s_barrier();          // all waves done reading buf[kt&1]
    __builtin_amdgcn_sched_barrier(0);
    if (kt + 2 < KT) stage(kt + 2, cbuf);  // overwrite consumed buffer; 2 new loads
  }

  // ---- epilogue: stage C (128x128 bf16 = 32 KB) in smem, chunk-swizzled, 16B stores ----
  float bcol[2];
#pragma unroll
  for (int ni = 0; ni < 2; ni++)
    bcol[ni] = bias[e * NCOL + cb * 128 + wc * 32 + ni * 16 + lc];

#pragma unroll
  for (int mi = 0; mi < 2; mi++) {
#pragma unroll
    for (int r4 = 0; r4 < 4; r4++) {
      int lrow = wr * 32 + mi * 16 + lr * 4 + r4;
      float p = 1.f;
      if constexpr (MODE == 1)
        p = (rb * 128 + lrow < ce) ? probs[rl[lrow]] : 0.f;
#pragma unroll
      for (int ni = 0; ni < 2; ni++) {
        int col = wc * 32 + ni * 16 + lc;
        float x = acc[mi][ni][r4] + bcol[ni];
        if constexpr (MODE == 0)
          x = gelu_f(x);
        else
          x *= p;
        int jc = col >> 3;   // 16B chunk within 256B row; swizzle vs row
        *(unsigned short*)(smem + lrow * 256 + ((jc ^ (lrow & 15)) << 4) + (col & 7) * 2) = f2bf(x);
      }
    }
  }
  __syncthreads();

  int row = t >> 3, q = t & 7;   // 8 threads/row, 32B each
  if (rb * 128 + row < ce) {
    int rid = rl[row];
    char* dst = (char*)(dstbuf + (long)rid * NCOL + cb * 128) + q * 32;
#pragma unroll
    for (int i = 0; i < 2; i++) {
      int jc = q * 2 + i;
      *(int4*)(dst + i * 16) = *(const int4*)(smem + row * 256 + ((jc ^ (row & 15)) << 4));
    }
  }
}

// ---------------- merge: out[n] = Y[2n] + Y[2n+1]  (bf16 -> f32) ----------------
typedef short short8v __attribute__((ext_vector_type(8)));
__global__ __launch_bounds__(256) void merge_kernel(const unsigned short* __restrict__ Y,
                                                    float* __restrict__ out) {
  int i = blockIdx.x * 256 + threadIdx.x;   // 1M chunks of 8 elems
  int n = i >> 7, c = (i & 127) * 8;
  const short8v a = *(const short8v*)(Y + (long)(2 * n) * HDIM + c);
  const short8v b = *(const short8v*)(Y + (long)(2 * n + 1) * HDIM + c);
  float4 o0, o1;
#pragma unroll
  for (int k = 0; k < 8; k++) {
    float v = bf2f((unsigned short)a[k]) + bf2f((unsigned short)b[k]);
    if (k < 4) (&o0.x)[k] = v; else (&o1.x)[k - 4] = v;
  }
  float4* dst = (float4*)(out + (long)n * HDIM + c);
  dst[0] = o0; dst[1] = o1;
}

extern "C" void kernel_launch(void* const* d_in, const int* in_sizes, int n_in,
                              void* d_out, int out_size, void* d_ws, size_t ws_size,
                              hipStream_t stream) {
  const float* tokens   = (const float*)d_in[0];
  const float* router_w = (const float*)d_in[1];
  const float* w1       = (const float*)d_in[2];
  const float* b1       = (const float*)d_in[3];
  const float* w2       = (const float*)d_in[4];
  const float* b2       = (const float*)d_in[5];
  float* out = (float*)d_out;

  // ws layout (bytes):
  //   0        counts[8]
  //   64       rowids[8][16384] int          (512 KiB)
  //   +512K    probs[16384] f32              (64 KiB)
  //   +64K     pair[8192] int                (32 KiB)
  //   then     cnt0[8], cnt1[8], wlb0[8*S0], wlb1[8*S1]  (~17 KiB)
  //   1 MiB    tokens_bf16 [8192][1024]      (16 MiB)
  //   +16M     w1b [8][2048][1024] bf16      (32 MiB)  <- becomes Ybuf after gemm0
  //   +48M     w2b [8][1024][2048] bf16      (32 MiB)
  //   +80M     Hbuf [16384][2048] bf16       (64 MiB)   total ~145 MiB
  char* ws = (char*)d_ws;
  int*            counts = (int*)ws;
  int*            rowids = (int*)(ws + 64);
  float*          probs  = (float*)(ws + 64 + NEXP * CAP * 4);
  int*            pair   = (int*)(ws + 64 + NEXP * CAP * 4 + N_TOK * 2 * 4);
  char*           wlbase = ws + 64 + NEXP * CAP * 4 + N_TOK * 2 * 4 + N_TOK * 4;
  int*            cnt0   = (int*)wlbase;
  int*            cnt1   = (int*)(wlbase + 64);
  int*            wlb0   = (int*)(wlbase + 128);
  int*            wlb1   = (int*)(wlbase + 128 + 8 * S0 * 4);
  unsigned short* tokb   = (unsigned short*)(ws + (1u << 20));
  unsigned short* w1b    = (unsigned short*)(ws + (1u << 20) + 16777216u);
  unsigned short* w2b    = (unsigned short*)(ws + (1u << 20) + 16777216u + 33554432u);
  unsigned short* Hbuf   = (unsigned short*)(ws + (1u << 20) + 16777216u + 67108864u);
  unsigned short* Ybuf   = w1b;  // w1 weights dead after gemm0; 32 MiB = 16384x1024 bf16

  cvt2_kernel<<<4096, 256, 0, stream>>>(w1, w1b, NEXP * 2048 * 1024 / 4,
                                        w2, w2b, NEXP * 1024 * 2048 / 4);
  router_kernel<<<N_TOK / 4, 256, 0, stream>>>(tokens, router_w, tokb, pair, probs);
  dispatch_kernel<<<NEXP, 1024, 0, stream>>>(pair, counts, rowids);
  worklist_kernel<<<1, 64, 0, stream>>>(counts, wlb0, cnt0, wlb1, cnt1);
  moe_gemm<0><<<8 * S0, 1024, 0, stream>>>(tokb, w1b, b1, counts, rowids, wlb0, cnt0, probs, Hbuf);
  moe_gemm<1><<<8 * S1, 1024, 0, stream>>>(Hbuf, w2b, b2, counts, rowids, wlb1, cnt1, probs, Ybuf);
  merge_kernel<<<N_TOK * HDIM / 8 / 256, 256, 0, stream>>>(Ybuf, out);
}

// Round 23
// 263.183 us; speedup vs baseline: 1.2985x; 1.0372x over previous
//
#include <hip/hip_runtime.h>
#include <stdint.h>

#define N_TOK 8192
#define HDIM  1024
#define NEXP  8
#define CAP   16384   // per-expert rowid list capacity
#define S0    320     // grid stride gemm0 (>= sum_e ceil(nt_e/2)*4 = 288)
#define S1    192     // grid stride gemm1 (>= sum_e ceil(nt_e/4)*4 = 160)

typedef __bf16 bf16x8 __attribute__((ext_vector_type(8)));
typedef float  f32x4  __attribute__((ext_vector_type(4)));

__device__ inline unsigned short f2bf(float f) {
  union { float f; unsigned u; } v; v.f = f;
  return (unsigned short)((v.u + 0x7fffu + ((v.u >> 16) & 1u)) >> 16);  // RNE
}

__device__ inline float bf2f(unsigned short b) {
  union { unsigned u; float f; } v; v.u = (unsigned)b << 16; return v.f;
}

// tanh-form gelu (max |err| vs exact erf-gelu ~1e-3, far under 2.7e-2 threshold)
__device__ inline float gelu_f(float x) {
  float y = 0.7978845608028654f * (x + 0.044715f * x * x * x);
  y = fminf(fmaxf(y, -15.f), 15.f);
  float t = __expf(2.f * y);
  return 0.5f * x * (1.f + (t - 1.f) / (t + 1.f));
}

__device__ inline void gld_lds16(const void* gptr, void* lptr) {
  __builtin_amdgcn_global_load_lds(
      (const __attribute__((address_space(1))) void*)(uintptr_t)gptr,
      (__attribute__((address_space(3))) void*)(uintptr_t)lptr,
      16, 0, 0);
}

// ---- prep: router (blocks 0..2047) OVERLAPPED with weight f32->bf16 cvt (blocks 2048+) ----
__global__ __launch_bounds__(256) void prep_kernel(
    const float* __restrict__ tokens, const float* __restrict__ rw,
    unsigned short* __restrict__ tokb, int* __restrict__ pair,
    float* __restrict__ probs,
    const float* __restrict__ s1, unsigned short* __restrict__ d1, int n1,
    const float* __restrict__ s2, unsigned short* __restrict__ d2, int n2) {
  if (blockIdx.x < N_TOK / 4) {
    // ---- router: logits, top-2, softmax -> pair/probs (NO atomics) ----
    int wid = threadIdx.x >> 6, lane = threadIdx.x & 63;
    int n = blockIdx.x * 4 + wid;
    const float4* trow = (const float4*)(tokens + (size_t)n * HDIM);
    ushort4* tdst = (ushort4*)(tokb + (size_t)n * HDIM);
    float acc[NEXP];
#pragma unroll
    for (int e = 0; e < NEXP; e++) acc[e] = 0.f;
#pragma unroll
    for (int it = 0; it < 4; it++) {
      int c4 = it * 64 + lane;
      float4 tv = trow[c4];
      ushort4 o;
      o.x = f2bf(tv.x); o.y = f2bf(tv.y); o.z = f2bf(tv.z); o.w = f2bf(tv.w);
      tdst[c4] = o;
#pragma unroll
      for (int e = 0; e < NEXP; e++) {
        float4 w = ((const float4*)(rw + e * HDIM))[c4];
        acc[e] += tv.x * w.x + tv.y * w.y + tv.z * w.z + tv.w * w.w;
      }
    }
#pragma unroll
    for (int e = 0; e < NEXP; e++) {
#pragma unroll
      for (int off = 32; off > 0; off >>= 1) acc[e] += __shfl_xor(acc[e], off, 64);
    }
    if (lane == 0) {
      int e0 = 0; float sc0 = acc[0];
#pragma unroll
      for (int e = 1; e < NEXP; e++) if (acc[e] > sc0) { sc0 = acc[e]; e0 = e; }
      int e1 = -1; float sc1 = -3.4e38f;
#pragma unroll
      for (int e = 0; e < NEXP; e++) if (e != e0 && acc[e] > sc1) { sc1 = acc[e]; e1 = e; }
      float z  = expf(sc1 - sc0);
      float p0 = 1.f / (1.f + z);
      pair[n] = e0 | (e1 << 8);
      probs[2 * n]     = p0;
      probs[2 * n + 1] = z * p0;
    }
  } else {
    // ---- weight conversion, grid-stride over both tensors ----
    int i = (blockIdx.x - N_TOK / 4) * 256 + threadIdx.x;
    int stride = 4096 * 256;
    for (; i < n1 + n2; i += stride) {
      const float4* sp; ushort4* dp; int k;
      if (i < n1) { sp = (const float4*)s1; dp = (ushort4*)d1; k = i; }
      else        { sp = (const float4*)s2; dp = (ushort4*)d2; k = i - n1; }
      float4 v = sp[k];
      ushort4 o;
      o.x = f2bf(v.x); o.y = f2bf(v.y); o.z = f2bf(v.z); o.w = f2bf(v.w);
      dp[k] = o;
    }
  }
}

// ---------------- dispatch: deterministic per-expert compaction via LDS scan ----------------
__global__ __launch_bounds__(1024) void dispatch_kernel(
    const int* __restrict__ pair, int* __restrict__ counts,
    int* __restrict__ rowids) {
  int e = blockIdx.x;
  int t = threadIdx.x;
  __shared__ int sc[1024];
  int p8[8];
  int c = 0;
#pragma unroll
  for (int i = 0; i < 8; i++) {
    p8[i] = pair[t * 8 + i];
    c += ((p8[i] & 255) == e) + (((p8[i] >> 8) & 255) == e);
  }
  sc[t] = c;
  __syncthreads();
  for (int off = 1; off < 1024; off <<= 1) {
    int v = (t >= off) ? sc[t - off] : 0;
    __syncthreads();
    sc[t] += v;
    __syncthreads();
  }
  if (t == 1023) counts[e] = sc[1023];
  int* dst = rowids + e * CAP + (sc[t] - c);
#pragma unroll
  for (int i = 0; i < 8; i++) {
    int n = t * 8 + i;
    if ((p8[i] & 255) == e)        *dst++ = 2 * n;
    if (((p8[i] >> 8) & 255) == e) *dst++ = 2 * n + 1;
  }
}

// ---- inline descriptor: (role, j) -> (e, tile, cb); pure function of counts ----
// gemm0 role r: tile-half h=r>>2, cb-quad q=r&3 (cb in {4q..4q+3}, CB=16).
// gemm1 role r: tile-quarter tq=r>>1, cb-pair cp=r&1 (cb in {4cp..4cp+3}, CB=8).
// Order within role: expert-major, tile, then the role's 4 cb back-to-back (A-panel L2-hot).
template <int MODE>
__device__ inline bool find_desc(const int* counts, int role, int j,
                                 int& e, int& ti, int& cb) {
  int p = 0;
  for (int ee = 0; ee < NEXP; ee++) {
    int nt = (counts[ee] + 127) >> 7;
    int t0, t1;
    if constexpr (MODE == 0) {
      int h = role >> 2;
      int h0 = (nt + 1) >> 1;
      t0 = h ? h0 : 0; t1 = h ? nt : h0;
    } else {
      int tq = role >> 1;
      t0 = (nt * tq) >> 2; t1 = (nt * (tq + 1)) >> 2;
    }
    int ce = (t1 - t0) * 4;
    if (j < p + ce) {
      int loc = j - p;
      e  = ee;
      ti = t0 + (loc >> 2);
      cb = ((MODE == 0) ? (role & 3) : (role & 1)) * 4 + (loc & 3);
      return true;
    }
    p += ce;
  }
  return false;
}

// ------- gathered NT bf16 GEMM: 128x128 tile, BK=64 dbuf counted-vmcnt, 1024 THREADS -------
// 16 waves (4x4, 32x32 each, acc[2][2]); 2 blocks/CU x 16 waves -> ~22 waves/CU measured.
// Per K-step: vmcnt(2) -> s_barrier -> ds_read + 8 MFMA/wave -> s_barrier -> stage(t+2).
// Block->work mapping: role = bid&7 (XCD pin), j = bid>>3, descriptor computed inline.
template <int MODE>
__global__ __launch_bounds__(1024) void moe_gemm(
    const unsigned short* __restrict__ Abase,
    const unsigned short* __restrict__ Wb,
    const float* __restrict__ bias,
    const int* __restrict__ counts, const int* __restrict__ rowids,
    const float* __restrict__ probs,
    unsigned short* __restrict__ dstbuf) {
  constexpr int KT     = MODE ? 32 : 16;   // K / 64
  constexpr int NCOL   = MODE ? 1024 : 2048;
  constexpr int KDIM   = MODE ? 2048 : 1024;

  int role = blockIdx.x & 7;               // XCD pin
  int j    = blockIdx.x >> 3;
  int e, rb, cb;
  if (!find_desc<MODE>(counts, role, j, e, rb, cb)) return;
  int ce = counts[e];
  const int* rl = rowids + e * CAP + rb * 128;

  int t = threadIdx.x;
  // double buffer: per buf A[128][64]bf16 (16 KB) @0, B[128][64] @16384 -> 32 KB/buf
  __shared__ __align__(16) char smem[65536];

  // staging: 1024 threads, 1 A-chunk + 1 B-chunk each (16 B). chunk c = t -> byte c*16;
  // row = t>>3, phys col-chunk = t&7; source logical chunk jsrc = (t&7)^((t>>3)&7)
  int jsrc = (t & 7) ^ ((t >> 3) & 7);
  int rr0 = t >> 3;                        // 0..127
  int rid0 = (rb * 128 + rr0 < ce) ? rl[rr0] : rl[0];
  long arow = MODE ? (long)rid0 : (long)(rid0 >> 1);
  const char* asrc = (const char*)(Abase + arow * KDIM) + jsrc * 16;
  const char* bsrc = (const char*)(Wb + ((long)e * NCOL + cb * 128 + rr0) * KDIM) + jsrc * 16;

  auto stage = [&](int kt, char* buf) {
    gld_lds16(asrc + kt * 128, buf + t * 16);
    gld_lds16(bsrc + kt * 128, buf + 16384 + t * 16);
  };

  f32x4 acc[2][2];
#pragma unroll
  for (int mi = 0; mi < 2; mi++)
#pragma unroll
    for (int ni = 0; ni < 2; ni++) {
      f32x4 z = {0.f, 0.f, 0.f, 0.f};
      acc[mi][ni] = z;
    }

  int lane = t & 63, wid = t >> 6;
  int wr = wid >> 2, wc = wid & 3;        // 4x4 wave grid; per-wave 32 rows x 32 cols
  int lr = lane >> 4, lc = lane & 15;

  // prologue: tiles 0,1 in flight (4 loads/thread)
  stage(0, smem);
  stage(1, smem + 32768);

  for (int kt = 0; kt < KT; kt++) {
    if (kt + 1 < KT) {
      asm volatile("s_waitcnt vmcnt(2)" ::: "memory");   // tile kt landed; kt+1 in flight
    } else {
      asm volatile("s_waitcnt vmcnt(0)" ::: "memory");   // last tile
    }
    __builtin_amdgcn_s_barrier();
    __builtin_amdgcn_sched_barrier(0);
    char* cbuf = smem + ((kt & 1) << 15);
#pragma unroll
    for (int ks = 0; ks < 2; ks++) {
      bf16x8 af[2], bfv[2];
      int jj = ks * 4 + lr;
#pragma unroll
      for (int mi = 0; mi < 2; mi++) {
        int rr = wr * 32 + mi * 16 + lc;
        af[mi] = *(const bf16x8*)(cbuf + rr * 128 + ((jj ^ (rr & 7)) << 4));
      }
#pragma unroll
      for (int ni = 0; ni < 2; ni++) {
        int rr = wc * 32 + ni * 16 + lc;
        bfv[ni] = *(const bf16x8*)(cbuf + 16384 + rr * 128 + ((jj ^ (rr & 7)) << 4));
      }
      __builtin_amdgcn_s_setprio(1);
#pragma unroll
      for (int mi = 0; mi < 2; mi++)
#pragma unroll
        for (int ni = 0; ni < 2; ni++)
          acc[mi][ni] = __builtin_amdgcn_mfma_f32_16x16x32_bf16(af[mi], bfv[ni], acc[mi][ni], 0, 0, 0);
      __builtin_amdgcn_s_setprio(0);
    }
    __builtin_amdgcn_s_barrier();          // all waves done reading buf[kt&1]
    __builtin_amdgcn_sched_barrier(0);
    if (kt + 2 < KT) stage(kt + 2, cbuf);  // overwrite consumed buffer; 2 new loads
  }

  // ---- epilogue: stage C (128x128 bf16 = 32 KB) in smem, chunk-swizzled, 16B stores ----
  float bcol[2];
#pragma unroll
  for (int ni = 0; ni < 2; ni++)
    bcol[ni] = bias[e * NCOL + cb * 128 + wc * 32 + ni * 16 + lc];

#pragma unroll
  for (int mi = 0; mi < 2; mi++) {
#pragma unroll
    for (int r4 = 0; r4 < 4; r4++) {
      int lrow = wr * 32 + mi * 16 + lr * 4 + r4;
      float p = 1.f;
      if constexpr (MODE == 1)
        p = (rb * 128 + lrow < ce) ? probs[rl[lrow]] : 0.f;
#pragma unroll
      for (int ni = 0; ni < 2; ni++) {
        int col = wc * 32 + ni * 16 + lc;
        float x = acc[mi][ni][r4] + bcol[ni];
        if constexpr (MODE == 0)
          x = gelu_f(x);
        else
          x *= p;
        int jc = col >> 3;   // 16B chunk within 256B row; swizzle vs row
        *(unsigned short*)(smem + lrow * 256 + ((jc ^ (lrow & 15)) << 4) + (col & 7) * 2) = f2bf(x);
      }
    }
  }
  __syncthreads();

  int row = t >> 3, q = t & 7;   // 8 threads/row, 32B each
  if (rb * 128 + row < ce) {
    int rid = rl[row];
    char* dst = (char*)(dstbuf + (long)rid * NCOL + cb * 128) + q * 32;
#pragma unroll
    for (int i = 0; i < 2; i++) {
      int jc = q * 2 + i;
      *(int4*)(dst + i * 16) = *(const int4*)(smem + row * 256 + ((jc ^ (row & 15)) << 4));
    }
  }
}

// ---------------- merge: out[n] = Y[2n] + Y[2n+1]  (bf16 -> f32) ----------------
typedef short short8v __attribute__((ext_vector_type(8)));
__global__ __launch_bounds__(256) void merge_kernel(const unsigned short* __restrict__ Y,
                                                    float* __restrict__ out) {
  int i = blockIdx.x * 256 + threadIdx.x;   // 1M chunks of 8 elems
  int n = i >> 7, c = (i & 127) * 8;
  const short8v a = *(const short8v*)(Y + (long)(2 * n) * HDIM + c);
  const short8v b = *(const short8v*)(Y + (long)(2 * n + 1) * HDIM + c);
  float4 o0, o1;
#pragma unroll
  for (int k = 0; k < 8; k++) {
    float v = bf2f((unsigned short)a[k]) + bf2f((unsigned short)b[k]);
    if (k < 4) (&o0.x)[k] = v; else (&o1.x)[k - 4] = v;
  }
  float4* dst = (float4*)(out + (long)n * HDIM + c);
  dst[0] = o0; dst[1] = o1;
}

extern "C" void kernel_launch(void* const* d_in, const int* in_sizes, int n_in,
                              void* d_out, int out_size, void* d_ws, size_t ws_size,
                              hipStream_t stream) {
  const float* tokens   = (const float*)d_in[0];
  const float* router_w = (const float*)d_in[1];
  const float* w1       = (const float*)d_in[2];
  const float* b1       = (const float*)d_in[3];
  const float* w2       = (const float*)d_in[4];
  const float* b2       = (const float*)d_in[5];
  float* out = (float*)d_out;

  // ws layout (bytes):
  //   0        counts[8]
  //   64       rowids[8][16384] int          (512 KiB)
  //   +512K    probs[16384] f32              (64 KiB)
  //   +64K     pair[8192] int                (32 KiB)
  //   1 MiB    tokens_bf16 [8192][1024]      (16 MiB)
  //   +16M     w1b [8][2048][1024] bf16      (32 MiB)  <- becomes Ybuf after gemm0
  //   +48M     w2b [8][1024][2048] bf16      (32 MiB)
  //   +80M     Hbuf [16384][2048] bf16       (64 MiB)   total ~145 MiB
  char* ws = (char*)d_ws;
  int*            counts = (int*)ws;
  int*            rowids = (int*)(ws + 64);
  float*          probs  = (float*)(ws + 64 + NEXP * CAP * 4);
  int*            pair   = (int*)(ws + 64 + NEXP * CAP * 4 + N_TOK * 2 * 4);
  unsigned short* tokb   = (unsigned short*)(ws + (1u << 20));
  unsigned short* w1b    = (unsigned short*)(ws + (1u << 20) + 16777216u);
  unsigned short* w2b    = (unsigned short*)(ws + (1u << 20) + 16777216u + 33554432u);
  unsigned short* Hbuf   = (unsigned short*)(ws + (1u << 20) + 16777216u + 67108864u);
  unsigned short* Ybuf   = w1b;  // w1 weights dead after gemm0; 32 MiB = 16384x1024 bf16

  prep_kernel<<<N_TOK / 4 + 4096, 256, 0, stream>>>(
      tokens, router_w, tokb, pair, probs,
      w1, w1b, NEXP * 2048 * 1024 / 4,
      w2, w2b, NEXP * 1024 * 2048 / 4);
  dispatch_kernel<<<NEXP, 1024, 0, stream>>>(pair, counts, rowids);
  moe_gemm<0><<<8 * S0, 1024, 0, stream>>>(tokb, w1b, b1, counts, rowids, probs, Hbuf);
  moe_gemm<1><<<8 * S1, 1024, 0, stream>>>(Hbuf, w2b, b2, counts, rowids, probs, Ybuf);
  merge_kernel<<<N_TOK * HDIM / 8 / 256, 256, 0, stream>>>(Ybuf, out);
}